// Round 1
// 1411.879 us; speedup vs baseline: 1.0898x; 1.0898x over previous
//
#include <hip/hip_runtime.h>

#define N_NODES 100000
#define N_EDGES 3200000

typedef unsigned int u32;
typedef unsigned short u16;
typedef __bf16 bf16x8 __attribute__((ext_vector_type(8)));
typedef float floatx4 __attribute__((ext_vector_type(4)));

__device__ __forceinline__ float bf2f(u16 u) { return __uint_as_float(((u32)u) << 16); }
__device__ __forceinline__ u16 f2bf(float f) {
    u32 u = __float_as_uint(f);
    u += 0x7fffu + ((u >> 16) & 1u);
    return (u16)(u >> 16);
}
__device__ __forceinline__ float lrelu(float v) { return v > 0.f ? v : 0.01f * v; }

__device__ __forceinline__ floatx4 mfma_bf16(bf16x8 a, bf16x8 b, floatx4 c) {
    return __builtin_amdgcn_mfma_f32_16x16x32_bf16(a, b, c, 0, 0, 0);
}

union bfrag { u16 u[8]; bf16x8 v; };

// load 8 consecutive fp32, convert to bf16 fragment (needs 16B alignment)
__device__ __forceinline__ bf16x8 cvt8(const float* p) {
    float4 lo = *(const float4*)p;
    float4 hi = *(const float4*)(p + 4);
    bfrag r;
    r.u[0] = f2bf(lo.x); r.u[1] = f2bf(lo.y); r.u[2] = f2bf(lo.z); r.u[3] = f2bf(lo.w);
    r.u[4] = f2bf(hi.x); r.u[5] = f2bf(hi.y); r.u[6] = f2bf(hi.z); r.u[7] = f2bf(hi.w);
    return r.v;
}

// ---------------- weight pre-swizzle (fp32 -> bf16 MFMA B-fragments) ----------------
// B[k][n] fragment for 16x16x32: lane holds k = kt*32 + (lane>>4)*8 + j, n = nt*16 + (lane&15)
__global__ void k_prep(const float* Wdes, const float* Wtwt, const float* Wnum, const float* Wcat,
                       const float* Win, const float* Wg1, const float* Wg2, const float* Wo1,
                       u16* Fdes, u16* Ftwt, u16* Fnum, u16* Fcat,
                       u16* Fin, u16* Fg1, u16* Fg2, u16* Fo1) {
    int tid = blockIdx.x * 256 + threadIdx.x;
    if (tid >= 228 * 64) return;
    int t = tid >> 6, lane = tid & 63;
    int quad = lane >> 4, l16 = lane & 15;
    const float* W; u16* F; int kt, nt, Nout, Kv, fi;
    if (t < 96) {
        int u = t; W = Wdes; F = Fdes;
        if (u >= 48) { u -= 48; W = Wtwt; F = Ftwt; }
        kt = u >> 1; nt = u & 1; Nout = 32; Kv = 768; fi = kt * 2 + nt;
    } else if (t < 100) {
        int u = t - 96; W = Wnum; F = Fnum; Kv = 6;
        if (u >= 2) { u -= 2; W = Wcat; F = Fcat; Kv = 11; }
        kt = 0; nt = u; Nout = 32; fi = nt;
    } else {
        int u = t - 100;
        if (u < 32)      { W = Win; F = Fin; }
        else if (u < 64) { W = Wg1; F = Fg1; u -= 32; }
        else if (u < 96) { W = Wg2; F = Fg2; u -= 64; }
        else             { W = Wo1; F = Fo1; u -= 96; }
        kt = u >> 3; nt = u & 7; Nout = 128; Kv = 128; fi = kt * 8 + nt;
    }
    u16* dst = F + ((size_t)(fi * 64 + lane)) * 8;
    int n = nt * 16 + l16;
    for (int j = 0; j < 8; j++) {
        int k = kt * 32 + quad * 8 + j;
        dst[j] = (k < Kv) ? f2bf(W[(size_t)k * Nout + n]) : (u16)0;
    }
}

// ---------------- CSR build ----------------
__global__ void k_hist(const int* dst, u32* cnt) {
    int e = blockIdx.x * 256 + threadIdx.x;
    atomicAdd(&cnt[dst[e]], 1u);
}

__global__ void k_dinv(const u32* cnt, float* dinv) {
    int i = blockIdx.x * 256 + threadIdx.x;
    if (i < N_NODES) dinv[i] = rsqrtf((float)(cnt[i] + 1));
}

__global__ void k_scan_a(const u32* cnt, u32* row_ptr, u32* partials) {
    __shared__ u32 s[1024];
    int i = blockIdx.x * 1024 + threadIdx.x;
    u32 v = (i < N_NODES) ? cnt[i] : 0u;
    s[threadIdx.x] = v; __syncthreads();
    for (int off = 1; off < 1024; off <<= 1) {
        u32 t = (threadIdx.x >= off) ? s[threadIdx.x - off] : 0u;
        __syncthreads(); s[threadIdx.x] += t; __syncthreads();
    }
    if (i < N_NODES) row_ptr[i] = s[threadIdx.x] - v;
    if (threadIdx.x == 1023) partials[blockIdx.x] = s[1023];
}

__global__ void k_scan_b(u32* partials) {
    __shared__ u32 s[128];
    u32 v = (threadIdx.x < 98) ? partials[threadIdx.x] : 0u;
    s[threadIdx.x] = v; __syncthreads();
    for (int off = 1; off < 128; off <<= 1) {
        u32 t = (threadIdx.x >= off) ? s[threadIdx.x - off] : 0u;
        __syncthreads(); s[threadIdx.x] += t; __syncthreads();
    }
    if (threadIdx.x < 98) partials[threadIdx.x] = s[threadIdx.x] - v;
}

__global__ void k_scan_c(u32* row_ptr, const u32* partials, u32* cursor) {
    int i = blockIdx.x * 1024 + threadIdx.x;
    if (i < N_NODES) {
        u32 r = row_ptr[i] + partials[blockIdx.x];
        row_ptr[i] = r; cursor[i] = r;
    }
}

// ---------------- bucketed CSR fill ----------------
// WRITE-LOCALITY FIX: old k_fill scattered 4B writes across the full 12.8MB col
// array -> every 64B line written back with ~1 valid entry (WRITE_SIZE ~195MB,
// 16x amplification). Instead: 20 dst-range buckets of 5000 nodes (~640KB of col
// each), bucket-major in blockIdx so the ~2048 concurrently-resident blocks share
// a 2-3 bucket (~2MB) window that stays L2-resident; each col line accumulates
// ~16 entries before one write-back. dst stream (12.8MB) is L3-resident across
// all 20 passes. Intra-row col order is arbitrary (gather only sums), and each
// node's cursor is only touched during its own bucket's pass -> semantics
// identical to the single-pass version.
#define FILL_K 20          // buckets: 100000/20 = 5000 nodes each
#define FILL_C 625         // chunks per bucket: 625 * 5120 = 3,200,000 edges exact
__global__ __launch_bounds__(256) void k_fill(const int* __restrict__ src,
                                              const int* __restrict__ dst,
                                              u32* cursor, u32* col) {
    int bucket = blockIdx.x / FILL_C;
    int chunk  = blockIdx.x % FILL_C;
    int lo = bucket * (N_NODES / FILL_K);
    int hi = lo + (N_NODES / FILL_K);
    const int4* dst4 = (const int4*)dst;
    int base4 = chunk * 1280;            // 5120 edges / 4 per int4
    for (int it = 0; it < 5; it++) {
        int i4 = base4 + it * 256 + threadIdx.x;
        int4 d = dst4[i4];
        int e = i4 * 4;
        #pragma unroll
        for (int c = 0; c < 4; c++) {
            int dv = (&d.x)[c];
            if (dv >= lo && dv < hi) {
                u32 p = atomicAdd(&cursor[dv], 1u);
                col[p] = (u32)src[e + c];
            }
        }
    }
}

// ---------------- encoder: 4 projections + lrelu + concat + W_in + lrelu, out scaled by dinv ----------------
__global__ __launch_bounds__(256) void k_encoder(
    const float* des, const float* twt, const float* nump, const float* catp,
    const u16* Fdes, const u16* Ftwt, const u16* Fnum, const u16* Fcat, const u16* Fin,
    const float* bdes, const float* btwt, const float* bnum, const float* bcat, const float* bin,
    const float* dinv, u16* xs) {
    __shared__ u16 h0[64][136];
    int tid = threadIdx.x, wave = tid >> 6, lane = tid & 63, quad = lane >> 4, l16 = lane & 15;
    int rowbase = blockIdx.x * 64 + wave * 16;
    int arow = min(rowbase + l16, N_NODES - 1);

    for (int m = 0; m < 2; m++) {
        const float* X = m ? twt : des;
        const u16* F = m ? Ftwt : Fdes;
        const float* B = m ? btwt : bdes;
        floatx4 c0 = {0, 0, 0, 0}, c1 = {0, 0, 0, 0};
        for (int kt = 0; kt < 24; kt++) {
            bf16x8 a = cvt8(X + (size_t)arow * 768 + kt * 32 + quad * 8);
            bf16x8 b0 = *(const bf16x8*)(F + ((size_t)((kt * 2 + 0) * 64 + lane)) * 8);
            bf16x8 b1 = *(const bf16x8*)(F + ((size_t)((kt * 2 + 1) * 64 + lane)) * 8);
            c0 = mfma_bf16(a, b0, c0);
            c1 = mfma_bf16(a, b1, c1);
        }
        int cb = m * 32;
        for (int r = 0; r < 4; r++) {
            int rl = wave * 16 + quad * 4 + r;
            h0[rl][cb + l16]      = f2bf(lrelu(c0[r] + B[l16]));
            h0[rl][cb + 16 + l16] = f2bf(lrelu(c1[r] + B[16 + l16]));
        }
    }
    {
        bfrag a; bfrag a2;
        for (int j = 0; j < 8; j++) {
            int k = quad * 8 + j;
            a.u[j]  = (k < 6)  ? f2bf(nump[(size_t)arow * 6 + k])  : (u16)0;
            a2.u[j] = (k < 11) ? f2bf(catp[(size_t)arow * 11 + k]) : (u16)0;
        }
        floatx4 c0 = {0,0,0,0}, c1 = {0,0,0,0}, c2 = {0,0,0,0}, c3 = {0,0,0,0};
        bf16x8 b0 = *(const bf16x8*)(Fnum + (size_t)(0 * 64 + lane) * 8);
        bf16x8 b1 = *(const bf16x8*)(Fnum + (size_t)(1 * 64 + lane) * 8);
        bf16x8 b2 = *(const bf16x8*)(Fcat + (size_t)(0 * 64 + lane) * 8);
        bf16x8 b3 = *(const bf16x8*)(Fcat + (size_t)(1 * 64 + lane) * 8);
        c0 = mfma_bf16(a.v, b0, c0);
        c1 = mfma_bf16(a.v, b1, c1);
        c2 = mfma_bf16(a2.v, b2, c2);
        c3 = mfma_bf16(a2.v, b3, c3);
        for (int r = 0; r < 4; r++) {
            int rl = wave * 16 + quad * 4 + r;
            h0[rl][64 + l16]  = f2bf(lrelu(c0[r] + bnum[l16]));
            h0[rl][80 + l16]  = f2bf(lrelu(c1[r] + bnum[16 + l16]));
            h0[rl][96 + l16]  = f2bf(lrelu(c2[r] + bcat[l16]));
            h0[rl][112 + l16] = f2bf(lrelu(c3[r] + bcat[16 + l16]));
        }
    }
    __syncthreads();
    floatx4 acc[8];
    for (int nt = 0; nt < 8; nt++) acc[nt] = (floatx4){0, 0, 0, 0};
    for (int kt = 0; kt < 4; kt++) {
        bf16x8 a = *(const bf16x8*)&h0[wave * 16 + l16][kt * 32 + quad * 8];
        for (int nt = 0; nt < 8; nt++) {
            bf16x8 b = *(const bf16x8*)(Fin + (size_t)((kt * 8 + nt) * 64 + lane) * 8);
            acc[nt] = mfma_bf16(a, b, acc[nt]);
        }
    }
    for (int nt = 0; nt < 8; nt++)
        for (int r = 0; r < 4; r++) {
            int grow = rowbase + quad * 4 + r;
            if (grow < N_NODES) {
                float v = lrelu(acc[nt][r] + bin[nt * 16 + l16]);
                xs[(size_t)grow * 128 + nt * 16 + l16] = f2bf(dinv[grow] * v);
            }
        }
}

// ---------------- gather: zs[d] = bf16( dinv[d] * (sum_{s in N(d)} xs[s] + xs[d]) ) ----------------
__global__ __launch_bounds__(256) void k_gather(const u16* xs, u16* zs, const u32* row_ptr,
                                                const u32* cnt, const float* dinv, const u32* col) {
    int wave = threadIdx.x >> 6, lane = threadIdx.x & 63;
    int node = blockIdx.x * 4 + wave;
    const u32* xr = (const u32*)xs;
    u32 self = xr[(size_t)node * 64 + lane];
    float a0 = bf2f((u16)(self & 0xffff)), a1 = bf2f((u16)(self >> 16));
    u32 start = row_ptr[node];
    u32 m = cnt[node];
    for (u32 base = 0; base < m; base += 64) {
        u32 idx = base + lane;
        int c = (idx < m) ? (int)col[start + idx] : 0;
        int kmax = (int)min(64u, m - base);
        for (int j = 0; j < kmax; j++) {
            int s = __shfl(c, j);
            u32 w = xr[(size_t)s * 64 + lane];
            a0 += bf2f((u16)(w & 0xffff));
            a1 += bf2f((u16)(w >> 16));
        }
    }
    float dv = dinv[node];
    u32 o = (u32)f2bf(dv * a0) | ((u32)f2bf(dv * a1) << 16);
    ((u32*)zs)[(size_t)node * 64 + lane] = o;
}

// ---------------- conv1 GEMM: xs = bf16( dinv[row] * (zs @ Wg1 + b_g1) ) ----------------
__global__ __launch_bounds__(256) void k_gemm_g1(const u16* zs, const u16* Fg1, const float* bg1,
                                                 const float* dinv, u16* xs) {
    int tid = threadIdx.x, wave = tid >> 6, lane = tid & 63, quad = lane >> 4, l16 = lane & 15;
    int rowbase = blockIdx.x * 64 + wave * 16;
    int arow = min(rowbase + l16, N_NODES - 1);
    floatx4 acc[8];
    for (int nt = 0; nt < 8; nt++) acc[nt] = (floatx4){0, 0, 0, 0};
    for (int kt = 0; kt < 4; kt++) {
        bf16x8 a = *(const bf16x8*)(zs + (size_t)arow * 128 + kt * 32 + quad * 8);
        for (int nt = 0; nt < 8; nt++) {
            bf16x8 b = *(const bf16x8*)(Fg1 + (size_t)((kt * 8 + nt) * 64 + lane) * 8);
            acc[nt] = mfma_bf16(a, b, acc[nt]);
        }
    }
    for (int nt = 0; nt < 8; nt++)
        for (int r = 0; r < 4; r++) {
            int grow = rowbase + quad * 4 + r;
            if (grow < N_NODES) {
                float v = acc[nt][r] + bg1[nt * 16 + l16];
                xs[(size_t)grow * 128 + nt * 16 + l16] = f2bf(dinv[grow] * v);
            }
        }
}

// ---------------- tail: conv2 GEMM + o1 GEMM(lrelu) + o2 dots (fp32 out) ----------------
__global__ __launch_bounds__(256) void k_tail(const u16* zs, const u16* Fg2, const float* bg2,
                                              const u16* Fo1, const float* bo1,
                                              const float* Wo2, const float* bo2, float* out) {
    __shared__ u16 t0[64][136];
    __shared__ float t1[64][130];
    int tid = threadIdx.x, wave = tid >> 6, lane = tid & 63, quad = lane >> 4, l16 = lane & 15;
    int rowbase = blockIdx.x * 64 + wave * 16;
    int arow = min(rowbase + l16, N_NODES - 1);
    floatx4 acc[8];
    for (int nt = 0; nt < 8; nt++) acc[nt] = (floatx4){0, 0, 0, 0};
    for (int kt = 0; kt < 4; kt++) {
        bf16x8 a = *(const bf16x8*)(zs + (size_t)arow * 128 + kt * 32 + quad * 8);
        for (int nt = 0; nt < 8; nt++) {
            bf16x8 b = *(const bf16x8*)(Fg2 + (size_t)((kt * 8 + nt) * 64 + lane) * 8);
            acc[nt] = mfma_bf16(a, b, acc[nt]);
        }
    }
    for (int nt = 0; nt < 8; nt++)
        for (int r = 0; r < 4; r++) {
            int rl = wave * 16 + quad * 4 + r;
            t0[rl][nt * 16 + l16] = f2bf(acc[nt][r] + bg2[nt * 16 + l16]);
        }
    __syncthreads();
    for (int nt = 0; nt < 8; nt++) acc[nt] = (floatx4){0, 0, 0, 0};
    for (int kt = 0; kt < 4; kt++) {
        bf16x8 a = *(const bf16x8*)&t0[wave * 16 + l16][kt * 32 + quad * 8];
        for (int nt = 0; nt < 8; nt++) {
            bf16x8 b = *(const bf16x8*)(Fo1 + (size_t)((kt * 8 + nt) * 64 + lane) * 8);
            acc[nt] = mfma_bf16(a, b, acc[nt]);
        }
    }
    for (int nt = 0; nt < 8; nt++)
        for (int r = 0; r < 4; r++) {
            int rl = wave * 16 + quad * 4 + r;
            t1[rl][nt * 16 + l16] = lrelu(acc[nt][r] + bo1[nt * 16 + l16]);
        }
    __syncthreads();
    if (tid < 128) {
        int nl = tid >> 1, j = tid & 1;
        int grow = blockIdx.x * 64 + nl;
        if (grow < N_NODES) {
            float s = bo2[j];
            for (int k = 0; k < 128; k++) s += t1[nl][k] * Wo2[k * 2 + j];
            out[(size_t)grow * 2 + j] = s;
        }
    }
}

extern "C" void kernel_launch(void* const* d_in, const int* in_sizes, int n_in,
                              void* d_out, int out_size, void* d_ws, size_t ws_size,
                              hipStream_t stream) {
    const float* des  = (const float*)d_in[0];
    const float* twt  = (const float*)d_in[1];
    const float* nump = (const float*)d_in[2];
    const float* catp = (const float*)d_in[3];
    const int* ei   = (const int*)d_in[4];
    const int* esrc = ei;
    const int* edst = ei + N_EDGES;
    const float* Wdes = (const float*)d_in[6];  const float* bdes = (const float*)d_in[7];
    const float* Wtwt = (const float*)d_in[8];  const float* btwt = (const float*)d_in[9];
    const float* Wnum = (const float*)d_in[10]; const float* bnum = (const float*)d_in[11];
    const float* Wcat = (const float*)d_in[12]; const float* bcat = (const float*)d_in[13];
    const float* Win  = (const float*)d_in[14]; const float* bin  = (const float*)d_in[15];
    const float* Wg1  = (const float*)d_in[16]; const float* bg1  = (const float*)d_in[17];
    const float* Wg2  = (const float*)d_in[18]; const float* bg2  = (const float*)d_in[19];
    const float* Wo1  = (const float*)d_in[20]; const float* bo1  = (const float*)d_in[21];
    const float* Wo2  = (const float*)d_in[22]; const float* bo2  = (const float*)d_in[23];

    char* ws = (char*)d_ws;
    size_t off = 0;
    auto alloc = [&](size_t b) { off = (off + 511) & ~(size_t)511; size_t o = off; off += b; return o; };
    u16* Fdes = (u16*)(ws + alloc(49152));
    u16* Ftwt = (u16*)(ws + alloc(49152));
    u16* Fnum = (u16*)(ws + alloc(2048));
    u16* Fcat = (u16*)(ws + alloc(2048));
    u16* Fin  = (u16*)(ws + alloc(32768));
    u16* Fg1  = (u16*)(ws + alloc(32768));
    u16* Fg2  = (u16*)(ws + alloc(32768));
    u16* Fo1  = (u16*)(ws + alloc(32768));
    u32* cnt     = (u32*)(ws + alloc((size_t)N_NODES * 4));
    float* dinv  = (float*)(ws + alloc((size_t)N_NODES * 4));
    u32* row_ptr = (u32*)(ws + alloc((size_t)(N_NODES + 1) * 4));
    u32* cursor  = (u32*)(ws + alloc((size_t)N_NODES * 4));
    u32* partials= (u32*)(ws + alloc(1024));
    u32* col     = (u32*)(ws + alloc((size_t)N_EDGES * 4));
    u16* xs      = (u16*)(ws + alloc((size_t)N_NODES * 128 * 2));
    u16* zs      = (u16*)(ws + alloc((size_t)N_NODES * 128 * 2));

    hipMemsetAsync(cnt, 0, (size_t)N_NODES * 4, stream);
    k_prep<<<57, 256, 0, stream>>>(Wdes, Wtwt, Wnum, Wcat, Win, Wg1, Wg2, Wo1,
                                   Fdes, Ftwt, Fnum, Fcat, Fin, Fg1, Fg2, Fo1);
    k_hist<<<N_EDGES / 256, 256, 0, stream>>>(edst, cnt);
    k_dinv<<<(N_NODES + 255) / 256, 256, 0, stream>>>(cnt, dinv);
    k_scan_a<<<98, 1024, 0, stream>>>(cnt, row_ptr, partials);
    k_scan_b<<<1, 128, 0, stream>>>(partials);
    k_scan_c<<<98, 1024, 0, stream>>>(row_ptr, partials, cursor);
    k_fill<<<FILL_K * FILL_C, 256, 0, stream>>>(esrc, edst, cursor, col);
    k_encoder<<<1563, 256, 0, stream>>>(des, twt, nump, catp,
                                        Fdes, Ftwt, Fnum, Fcat, Fin,
                                        bdes, btwt, bnum, bcat, bin, dinv, xs);
    k_gather<<<25000, 256, 0, stream>>>(xs, zs, row_ptr, cnt, dinv, col);
    k_gemm_g1<<<1563, 256, 0, stream>>>(zs, Fg1, bg1, dinv, xs);
    k_gather<<<25000, 256, 0, stream>>>(xs, zs, row_ptr, cnt, dinv, col);
    k_tail<<<1563, 256, 0, stream>>>(zs, Fg2, bg2, Fo1, bo1, Wo2, bo2, (float*)d_out);
}

// Round 2
// 1252.993 us; speedup vs baseline: 1.2280x; 1.1268x over previous
//
#include <hip/hip_runtime.h>

#define N_NODES 100000
#define N_EDGES 3200000

typedef unsigned int u32;
typedef unsigned short u16;
typedef __bf16 bf16x8 __attribute__((ext_vector_type(8)));
typedef float floatx4 __attribute__((ext_vector_type(4)));

__device__ __forceinline__ float bf2f(u16 u) { return __uint_as_float(((u32)u) << 16); }
__device__ __forceinline__ u16 f2bf(float f) {
    u32 u = __float_as_uint(f);
    u += 0x7fffu + ((u >> 16) & 1u);
    return (u16)(u >> 16);
}
__device__ __forceinline__ float lrelu(float v) { return v > 0.f ? v : 0.01f * v; }

__device__ __forceinline__ floatx4 mfma_bf16(bf16x8 a, bf16x8 b, floatx4 c) {
    return __builtin_amdgcn_mfma_f32_16x16x32_bf16(a, b, c, 0, 0, 0);
}

union bfrag { u16 u[8]; bf16x8 v; };

// pack two float4 into a bf16 MFMA fragment
__device__ __forceinline__ bf16x8 pack8(float4 lo, float4 hi) {
    bfrag r;
    r.u[0] = f2bf(lo.x); r.u[1] = f2bf(lo.y); r.u[2] = f2bf(lo.z); r.u[3] = f2bf(lo.w);
    r.u[4] = f2bf(hi.x); r.u[5] = f2bf(hi.y); r.u[6] = f2bf(hi.z); r.u[7] = f2bf(hi.w);
    return r.v;
}

// ---------------- weight pre-swizzle (fp32 -> bf16 MFMA B-fragments) ----------------
// B[k][n] fragment for 16x16x32: lane holds k = kt*32 + (lane>>4)*8 + j, n = nt*16 + (lane&15)
__global__ void k_prep(const float* Wdes, const float* Wtwt, const float* Wnum, const float* Wcat,
                       const float* Win, const float* Wg1, const float* Wg2, const float* Wo1,
                       u16* Fdes, u16* Ftwt, u16* Fnum, u16* Fcat,
                       u16* Fin, u16* Fg1, u16* Fg2, u16* Fo1) {
    int tid = blockIdx.x * 256 + threadIdx.x;
    if (tid >= 228 * 64) return;
    int t = tid >> 6, lane = tid & 63;
    int quad = lane >> 4, l16 = lane & 15;
    const float* W; u16* F; int kt, nt, Nout, Kv, fi;
    if (t < 96) {
        int u = t; W = Wdes; F = Fdes;
        if (u >= 48) { u -= 48; W = Wtwt; F = Ftwt; }
        kt = u >> 1; nt = u & 1; Nout = 32; Kv = 768; fi = kt * 2 + nt;
    } else if (t < 100) {
        int u = t - 96; W = Wnum; F = Fnum; Kv = 6;
        if (u >= 2) { u -= 2; W = Wcat; F = Fcat; Kv = 11; }
        kt = 0; nt = u; Nout = 32; fi = nt;
    } else {
        int u = t - 100;
        if (u < 32)      { W = Win; F = Fin; }
        else if (u < 64) { W = Wg1; F = Fg1; u -= 32; }
        else if (u < 96) { W = Wg2; F = Fg2; u -= 64; }
        else             { W = Wo1; F = Fo1; u -= 96; }
        kt = u >> 3; nt = u & 7; Nout = 128; Kv = 128; fi = kt * 8 + nt;
    }
    u16* dst = F + ((size_t)(fi * 64 + lane)) * 8;
    int n = nt * 16 + l16;
    for (int j = 0; j < 8; j++) {
        int k = kt * 32 + quad * 8 + j;
        dst[j] = (k < Kv) ? f2bf(W[(size_t)k * Nout + n]) : (u16)0;
    }
}

// ---------------- CSR build ----------------
__global__ void k_hist(const int* dst, u32* cnt) {
    int e = blockIdx.x * 256 + threadIdx.x;
    atomicAdd(&cnt[dst[e]], 1u);
}

__global__ void k_dinv(const u32* cnt, float* dinv) {
    int i = blockIdx.x * 256 + threadIdx.x;
    if (i < N_NODES) dinv[i] = rsqrtf((float)(cnt[i] + 1));
}

__global__ void k_scan_a(const u32* cnt, u32* row_ptr, u32* partials) {
    __shared__ u32 s[1024];
    int i = blockIdx.x * 1024 + threadIdx.x;
    u32 v = (i < N_NODES) ? cnt[i] : 0u;
    s[threadIdx.x] = v; __syncthreads();
    for (int off = 1; off < 1024; off <<= 1) {
        u32 t = (threadIdx.x >= off) ? s[threadIdx.x - off] : 0u;
        __syncthreads(); s[threadIdx.x] += t; __syncthreads();
    }
    if (i < N_NODES) row_ptr[i] = s[threadIdx.x] - v;
    if (threadIdx.x == 1023) partials[blockIdx.x] = s[1023];
}

__global__ void k_scan_b(u32* partials) {
    __shared__ u32 s[128];
    u32 v = (threadIdx.x < 98) ? partials[threadIdx.x] : 0u;
    s[threadIdx.x] = v; __syncthreads();
    for (int off = 1; off < 128; off <<= 1) {
        u32 t = (threadIdx.x >= off) ? s[threadIdx.x - off] : 0u;
        __syncthreads(); s[threadIdx.x] += t; __syncthreads();
    }
    if (threadIdx.x < 98) partials[threadIdx.x] = s[threadIdx.x] - v;
}

__global__ void k_scan_c(u32* row_ptr, const u32* partials, u32* cursor) {
    int i = blockIdx.x * 1024 + threadIdx.x;
    if (i < N_NODES) {
        u32 r = row_ptr[i] + partials[blockIdx.x];
        row_ptr[i] = r; cursor[i] = r;
    }
}

// ---------------- bucketed CSR fill ----------------
// 20 dst-range buckets of 5000 nodes (~640KB of col each), bucket-major in
// blockIdx so concurrently-resident blocks share an L2-resident col window.
#define FILL_K 20
#define FILL_C 625
__global__ __launch_bounds__(256) void k_fill(const int* __restrict__ src,
                                              const int* __restrict__ dst,
                                              u32* cursor, u32* col) {
    int bucket = blockIdx.x / FILL_C;
    int chunk  = blockIdx.x % FILL_C;
    int lo = bucket * (N_NODES / FILL_K);
    int hi = lo + (N_NODES / FILL_K);
    const int4* dst4 = (const int4*)dst;
    int base4 = chunk * 1280;
    for (int it = 0; it < 5; it++) {
        int i4 = base4 + it * 256 + threadIdx.x;
        int4 d = dst4[i4];
        int e = i4 * 4;
        #pragma unroll
        for (int c = 0; c < 4; c++) {
            int dv = (&d.x)[c];
            if (dv >= lo && dv < hi) {
                u32 p = atomicAdd(&cursor[dv], 1u);
                col[p] = (u32)src[e + c];
            }
        }
    }
}

// ---------------- encoder: 4 projections + lrelu + concat + W_in + lrelu, out scaled by dinv ----
// LATENCY FIX: old loop had ~1 kt-iteration of loads in flight (VGPR=48,
// VALUBusy 8%, HBM 19%, nothing saturated). Register double-buffered pipeline:
// 4-kt groups (8x dwordx4 in flight), prefetch group g+1 during compute of g,
// g-loop fully unrolled so all buffer indices are compile-time (no scratch).
__global__ __launch_bounds__(256) void k_encoder(
    const float* des, const float* twt, const float* nump, const float* catp,
    const u16* Fdes, const u16* Ftwt, const u16* Fnum, const u16* Fcat, const u16* Fin,
    const float* bdes, const float* btwt, const float* bnum, const float* bcat, const float* bin,
    const float* dinv, u16* xs) {
    __shared__ u16 h0[64][136];
    int tid = threadIdx.x, wave = tid >> 6, lane = tid & 63, quad = lane >> 4, l16 = lane & 15;
    int rowbase = blockIdx.x * 64 + wave * 16;
    int arow = min(rowbase + l16, N_NODES - 1);

    for (int m = 0; m < 2; m++) {
        const float* X = m ? twt : des;
        const u16* F = m ? Ftwt : Fdes;
        const float* B = m ? btwt : bdes;
        const float4* X4 = (const float4*)(X + (size_t)arow * 768) + quad * 2;
        floatx4 c0 = {0, 0, 0, 0}, c1 = {0, 0, 0, 0};
        float4 A0[8], A1[8];
        #pragma unroll
        for (int i = 0; i < 4; i++) {         // prefetch group 0 (kt 0..3)
            A0[2 * i]     = X4[i * 8];
            A0[2 * i + 1] = X4[i * 8 + 1];
        }
        #pragma unroll
        for (int g = 0; g < 6; g++) {
            #pragma unroll
            for (int i = 0; i < 4; i++) {     // prefetch group g+1
                int kt = (g + 1) * 4 + i;
                if (g < 5) {
                    if (g & 1) { A0[2 * i] = X4[kt * 8]; A0[2 * i + 1] = X4[kt * 8 + 1]; }
                    else       { A1[2 * i] = X4[kt * 8]; A1[2 * i + 1] = X4[kt * 8 + 1]; }
                }
            }
            #pragma unroll
            for (int i = 0; i < 4; i++) {     // compute group g
                int kt = g * 4 + i;
                float4 lo = (g & 1) ? A1[2 * i]     : A0[2 * i];
                float4 hi = (g & 1) ? A1[2 * i + 1] : A0[2 * i + 1];
                bf16x8 a = pack8(lo, hi);
                bf16x8 b0 = *(const bf16x8*)(F + ((size_t)((kt * 2 + 0) * 64 + lane)) * 8);
                bf16x8 b1 = *(const bf16x8*)(F + ((size_t)((kt * 2 + 1) * 64 + lane)) * 8);
                c0 = mfma_bf16(a, b0, c0);
                c1 = mfma_bf16(a, b1, c1);
            }
        }
        int cb = m * 32;
        for (int r = 0; r < 4; r++) {
            int rl = wave * 16 + quad * 4 + r;
            h0[rl][cb + l16]      = f2bf(lrelu(c0[r] + B[l16]));
            h0[rl][cb + 16 + l16] = f2bf(lrelu(c1[r] + B[16 + l16]));
        }
    }
    {
        bfrag a; bfrag a2;
        for (int j = 0; j < 8; j++) {
            int k = quad * 8 + j;
            a.u[j]  = (k < 6)  ? f2bf(nump[(size_t)arow * 6 + k])  : (u16)0;
            a2.u[j] = (k < 11) ? f2bf(catp[(size_t)arow * 11 + k]) : (u16)0;
        }
        floatx4 c0 = {0,0,0,0}, c1 = {0,0,0,0}, c2 = {0,0,0,0}, c3 = {0,0,0,0};
        bf16x8 b0 = *(const bf16x8*)(Fnum + (size_t)(0 * 64 + lane) * 8);
        bf16x8 b1 = *(const bf16x8*)(Fnum + (size_t)(1 * 64 + lane) * 8);
        bf16x8 b2 = *(const bf16x8*)(Fcat + (size_t)(0 * 64 + lane) * 8);
        bf16x8 b3 = *(const bf16x8*)(Fcat + (size_t)(1 * 64 + lane) * 8);
        c0 = mfma_bf16(a.v, b0, c0);
        c1 = mfma_bf16(a.v, b1, c1);
        c2 = mfma_bf16(a2.v, b2, c2);
        c3 = mfma_bf16(a2.v, b3, c3);
        for (int r = 0; r < 4; r++) {
            int rl = wave * 16 + quad * 4 + r;
            h0[rl][64 + l16]  = f2bf(lrelu(c0[r] + bnum[l16]));
            h0[rl][80 + l16]  = f2bf(lrelu(c1[r] + bnum[16 + l16]));
            h0[rl][96 + l16]  = f2bf(lrelu(c2[r] + bcat[l16]));
            h0[rl][112 + l16] = f2bf(lrelu(c3[r] + bcat[16 + l16]));
        }
    }
    __syncthreads();
    floatx4 acc[8];
    for (int nt = 0; nt < 8; nt++) acc[nt] = (floatx4){0, 0, 0, 0};
    for (int kt = 0; kt < 4; kt++) {
        bf16x8 a = *(const bf16x8*)&h0[wave * 16 + l16][kt * 32 + quad * 8];
        for (int nt = 0; nt < 8; nt++) {
            bf16x8 b = *(const bf16x8*)(Fin + (size_t)((kt * 8 + nt) * 64 + lane) * 8);
            acc[nt] = mfma_bf16(a, b, acc[nt]);
        }
    }
    for (int nt = 0; nt < 8; nt++)
        for (int r = 0; r < 4; r++) {
            int grow = rowbase + quad * 4 + r;
            if (grow < N_NODES) {
                float v = lrelu(acc[nt][r] + bin[nt * 16 + l16]);
                xs[(size_t)grow * 128 + nt * 16 + l16] = f2bf(dinv[grow] * v);
            }
        }
}

// ---------------- gather: zs[d] = bf16( dinv[d] * (sum_{s in N(d)} xs[s] + xs[d]) ) ----------------
// MLP FIX: unroll neighbor loop x8 so 8 independent 4B/lane loads are in flight
// (was 1 dependent load per neighbor). Accumulation order unchanged -> bit-identical.
__global__ __launch_bounds__(256) void k_gather(const u16* xs, u16* zs, const u32* row_ptr,
                                                const u32* cnt, const float* dinv, const u32* col) {
    int wave = threadIdx.x >> 6, lane = threadIdx.x & 63;
    int node = blockIdx.x * 4 + wave;
    const u32* xr = (const u32*)xs;
    u32 self = xr[(size_t)node * 64 + lane];
    float a0 = bf2f((u16)(self & 0xffff)), a1 = bf2f((u16)(self >> 16));
    u32 start = row_ptr[node];
    u32 m = cnt[node];
    for (u32 base = 0; base < m; base += 64) {
        u32 idx = base + lane;
        int c = (idx < m) ? (int)col[start + idx] : 0;
        int kmax = (int)min(64u, m - base);
        int j = 0;
        for (; j + 8 <= kmax; j += 8) {
            u32 w[8];
            #pragma unroll
            for (int q = 0; q < 8; q++) {
                int s = __shfl(c, j + q);
                w[q] = xr[(size_t)s * 64 + lane];
            }
            #pragma unroll
            for (int q = 0; q < 8; q++) {
                a0 += bf2f((u16)(w[q] & 0xffff));
                a1 += bf2f((u16)(w[q] >> 16));
            }
        }
        for (; j < kmax; j++) {
            int s = __shfl(c, j);
            u32 w = xr[(size_t)s * 64 + lane];
            a0 += bf2f((u16)(w & 0xffff));
            a1 += bf2f((u16)(w >> 16));
        }
    }
    float dv = dinv[node];
    u32 o = (u32)f2bf(dv * a0) | ((u32)f2bf(dv * a1) << 16);
    ((u32*)zs)[(size_t)node * 64 + lane] = o;
}

// ---------------- conv1 GEMM: xs = bf16( dinv[row] * (zs @ Wg1 + b_g1) ) ----------------
__global__ __launch_bounds__(256) void k_gemm_g1(const u16* zs, const u16* Fg1, const float* bg1,
                                                 const float* dinv, u16* xs) {
    int tid = threadIdx.x, wave = tid >> 6, lane = tid & 63, quad = lane >> 4, l16 = lane & 15;
    int rowbase = blockIdx.x * 64 + wave * 16;
    int arow = min(rowbase + l16, N_NODES - 1);
    floatx4 acc[8];
    for (int nt = 0; nt < 8; nt++) acc[nt] = (floatx4){0, 0, 0, 0};
    for (int kt = 0; kt < 4; kt++) {
        bf16x8 a = *(const bf16x8*)(zs + (size_t)arow * 128 + kt * 32 + quad * 8);
        for (int nt = 0; nt < 8; nt++) {
            bf16x8 b = *(const bf16x8*)(Fg1 + (size_t)((kt * 8 + nt) * 64 + lane) * 8);
            acc[nt] = mfma_bf16(a, b, acc[nt]);
        }
    }
    for (int nt = 0; nt < 8; nt++)
        for (int r = 0; r < 4; r++) {
            int grow = rowbase + quad * 4 + r;
            if (grow < N_NODES) {
                float v = acc[nt][r] + bg1[nt * 16 + l16];
                xs[(size_t)grow * 128 + nt * 16 + l16] = f2bf(dinv[grow] * v);
            }
        }
}

// ---------------- tail: conv2 GEMM + o1 GEMM(lrelu) + o2 dots (fp32 out) ----------------
__global__ __launch_bounds__(256) void k_tail(const u16* zs, const u16* Fg2, const float* bg2,
                                              const u16* Fo1, const float* bo1,
                                              const float* Wo2, const float* bo2, float* out) {
    __shared__ u16 t0[64][136];
    __shared__ float t1[64][130];
    int tid = threadIdx.x, wave = tid >> 6, lane = tid & 63, quad = lane >> 4, l16 = lane & 15;
    int rowbase = blockIdx.x * 64 + wave * 16;
    int arow = min(rowbase + l16, N_NODES - 1);
    floatx4 acc[8];
    for (int nt = 0; nt < 8; nt++) acc[nt] = (floatx4){0, 0, 0, 0};
    for (int kt = 0; kt < 4; kt++) {
        bf16x8 a = *(const bf16x8*)(zs + (size_t)arow * 128 + kt * 32 + quad * 8);
        for (int nt = 0; nt < 8; nt++) {
            bf16x8 b = *(const bf16x8*)(Fg2 + (size_t)((kt * 8 + nt) * 64 + lane) * 8);
            acc[nt] = mfma_bf16(a, b, acc[nt]);
        }
    }
    for (int nt = 0; nt < 8; nt++)
        for (int r = 0; r < 4; r++) {
            int rl = wave * 16 + quad * 4 + r;
            t0[rl][nt * 16 + l16] = f2bf(acc[nt][r] + bg2[nt * 16 + l16]);
        }
    __syncthreads();
    for (int nt = 0; nt < 8; nt++) acc[nt] = (floatx4){0, 0, 0, 0};
    for (int kt = 0; kt < 4; kt++) {
        bf16x8 a = *(const bf16x8*)&t0[wave * 16 + l16][kt * 32 + quad * 8];
        for (int nt = 0; nt < 8; nt++) {
            bf16x8 b = *(const bf16x8*)(Fo1 + (size_t)((kt * 8 + nt) * 64 + lane) * 8);
            acc[nt] = mfma_bf16(a, b, acc[nt]);
        }
    }
    for (int nt = 0; nt < 8; nt++)
        for (int r = 0; r < 4; r++) {
            int rl = wave * 16 + quad * 4 + r;
            t1[rl][nt * 16 + l16] = lrelu(acc[nt][r] + bo1[nt * 16 + l16]);
        }
    __syncthreads();
    if (tid < 128) {
        int nl = tid >> 1, j = tid & 1;
        int grow = blockIdx.x * 64 + nl;
        if (grow < N_NODES) {
            float s = bo2[j];
            for (int k = 0; k < 128; k++) s += t1[nl][k] * Wo2[k * 2 + j];
            out[(size_t)grow * 2 + j] = s;
        }
    }
}

extern "C" void kernel_launch(void* const* d_in, const int* in_sizes, int n_in,
                              void* d_out, int out_size, void* d_ws, size_t ws_size,
                              hipStream_t stream) {
    const float* des  = (const float*)d_in[0];
    const float* twt  = (const float*)d_in[1];
    const float* nump = (const float*)d_in[2];
    const float* catp = (const float*)d_in[3];
    const int* ei   = (const int*)d_in[4];
    const int* esrc = ei;
    const int* edst = ei + N_EDGES;
    const float* Wdes = (const float*)d_in[6];  const float* bdes = (const float*)d_in[7];
    const float* Wtwt = (const float*)d_in[8];  const float* btwt = (const float*)d_in[9];
    const float* Wnum = (const float*)d_in[10]; const float* bnum = (const float*)d_in[11];
    const float* Wcat = (const float*)d_in[12]; const float* bcat = (const float*)d_in[13];
    const float* Win  = (const float*)d_in[14]; const float* bin  = (const float*)d_in[15];
    const float* Wg1  = (const float*)d_in[16]; const float* bg1  = (const float*)d_in[17];
    const float* Wg2  = (const float*)d_in[18]; const float* bg2  = (const float*)d_in[19];
    const float* Wo1  = (const float*)d_in[20]; const float* bo1  = (const float*)d_in[21];
    const float* Wo2  = (const float*)d_in[22]; const float* bo2  = (const float*)d_in[23];

    char* ws = (char*)d_ws;
    size_t off = 0;
    auto alloc = [&](size_t b) { off = (off + 511) & ~(size_t)511; size_t o = off; off += b; return o; };
    u16* Fdes = (u16*)(ws + alloc(49152));
    u16* Ftwt = (u16*)(ws + alloc(49152));
    u16* Fnum = (u16*)(ws + alloc(2048));
    u16* Fcat = (u16*)(ws + alloc(2048));
    u16* Fin  = (u16*)(ws + alloc(32768));
    u16* Fg1  = (u16*)(ws + alloc(32768));
    u16* Fg2  = (u16*)(ws + alloc(32768));
    u16* Fo1  = (u16*)(ws + alloc(32768));
    u32* cnt     = (u32*)(ws + alloc((size_t)N_NODES * 4));
    float* dinv  = (float*)(ws + alloc((size_t)N_NODES * 4));
    u32* row_ptr = (u32*)(ws + alloc((size_t)(N_NODES + 1) * 4));
    u32* cursor  = (u32*)(ws + alloc((size_t)N_NODES * 4));
    u32* partials= (u32*)(ws + alloc(1024));
    u32* col     = (u32*)(ws + alloc((size_t)N_EDGES * 4));
    u16* xs      = (u16*)(ws + alloc((size_t)N_NODES * 128 * 2));
    u16* zs      = (u16*)(ws + alloc((size_t)N_NODES * 128 * 2));

    hipMemsetAsync(cnt, 0, (size_t)N_NODES * 4, stream);
    k_prep<<<57, 256, 0, stream>>>(Wdes, Wtwt, Wnum, Wcat, Win, Wg1, Wg2, Wo1,
                                   Fdes, Ftwt, Fnum, Fcat, Fin, Fg1, Fg2, Fo1);
    k_hist<<<N_EDGES / 256, 256, 0, stream>>>(edst, cnt);
    k_dinv<<<(N_NODES + 255) / 256, 256, 0, stream>>>(cnt, dinv);
    k_scan_a<<<98, 1024, 0, stream>>>(cnt, row_ptr, partials);
    k_scan_b<<<1, 128, 0, stream>>>(partials);
    k_scan_c<<<98, 1024, 0, stream>>>(row_ptr, partials, cursor);
    k_fill<<<FILL_K * FILL_C, 256, 0, stream>>>(esrc, edst, cursor, col);
    k_encoder<<<1563, 256, 0, stream>>>(des, twt, nump, catp,
                                        Fdes, Ftwt, Fnum, Fcat, Fin,
                                        bdes, btwt, bnum, bcat, bin, dinv, xs);
    k_gather<<<25000, 256, 0, stream>>>(xs, zs, row_ptr, cnt, dinv, col);
    k_gemm_g1<<<1563, 256, 0, stream>>>(zs, Fg1, bg1, dinv, xs);
    k_gather<<<25000, 256, 0, stream>>>(xs, zs, row_ptr, cnt, dinv, col);
    k_tail<<<1563, 256, 0, stream>>>(zs, Fg2, bg2, Fo1, bo1, Wo2, bo2, (float*)d_out);
}

// Round 3
// 1222.178 us; speedup vs baseline: 1.2590x; 1.0252x over previous
//
#include <hip/hip_runtime.h>

#define N_NODES 100000
#define N_EDGES 3200000

typedef unsigned int u32;
typedef unsigned short u16;
typedef __bf16 bf16x8 __attribute__((ext_vector_type(8)));
typedef float floatx4 __attribute__((ext_vector_type(4)));

__device__ __forceinline__ float bf2f(u16 u) { return __uint_as_float(((u32)u) << 16); }
__device__ __forceinline__ u16 f2bf(float f) {
    u32 u = __float_as_uint(f);
    u += 0x7fffu + ((u >> 16) & 1u);
    return (u16)(u >> 16);
}
__device__ __forceinline__ float lrelu(float v) { return v > 0.f ? v : 0.01f * v; }

__device__ __forceinline__ floatx4 mfma_bf16(bf16x8 a, bf16x8 b, floatx4 c) {
    return __builtin_amdgcn_mfma_f32_16x16x32_bf16(a, b, c, 0, 0, 0);
}

union bfrag { u16 u[8]; bf16x8 v; };

// ---------------- weight pre-swizzle (fp32 -> bf16 MFMA B-fragments) ----------------
// B[k][n] fragment for 16x16x32: lane holds k = kt*32 + (lane>>4)*8 + j, n = nt*16 + (lane&15)
__global__ void k_prep(const float* Wdes, const float* Wtwt, const float* Wnum, const float* Wcat,
                       const float* Win, const float* Wg1, const float* Wg2, const float* Wo1,
                       u16* Fdes, u16* Ftwt, u16* Fnum, u16* Fcat,
                       u16* Fin, u16* Fg1, u16* Fg2, u16* Fo1) {
    int tid = blockIdx.x * 256 + threadIdx.x;
    if (tid >= 228 * 64) return;
    int t = tid >> 6, lane = tid & 63;
    int quad = lane >> 4, l16 = lane & 15;
    const float* W; u16* F; int kt, nt, Nout, Kv, fi;
    if (t < 96) {
        int u = t; W = Wdes; F = Fdes;
        if (u >= 48) { u -= 48; W = Wtwt; F = Ftwt; }
        kt = u >> 1; nt = u & 1; Nout = 32; Kv = 768; fi = kt * 2 + nt;
    } else if (t < 100) {
        int u = t - 96; W = Wnum; F = Fnum; Kv = 6;
        if (u >= 2) { u -= 2; W = Wcat; F = Fcat; Kv = 11; }
        kt = 0; nt = u; Nout = 32; fi = nt;
    } else {
        int u = t - 100;
        if (u < 32)      { W = Win; F = Fin; }
        else if (u < 64) { W = Wg1; F = Fg1; u -= 32; }
        else if (u < 96) { W = Wg2; F = Fg2; u -= 64; }
        else             { W = Wo1; F = Fo1; u -= 96; }
        kt = u >> 3; nt = u & 7; Nout = 128; Kv = 128; fi = kt * 8 + nt;
    }
    u16* dst = F + ((size_t)(fi * 64 + lane)) * 8;
    int n = nt * 16 + l16;
    for (int j = 0; j < 8; j++) {
        int k = kt * 32 + quad * 8 + j;
        dst[j] = (k < Kv) ? f2bf(W[(size_t)k * Nout + n]) : (u16)0;
    }
}

// ---------------- CSR build ----------------
__global__ void k_hist(const int* dst, u32* cnt) {
    int e = blockIdx.x * 256 + threadIdx.x;
    atomicAdd(&cnt[dst[e]], 1u);
}

__global__ void k_dinv(const u32* cnt, float* dinv) {
    int i = blockIdx.x * 256 + threadIdx.x;
    if (i < N_NODES) dinv[i] = rsqrtf((float)(cnt[i] + 1));
}

__global__ void k_scan_a(const u32* cnt, u32* row_ptr, u32* partials) {
    __shared__ u32 s[1024];
    int i = blockIdx.x * 1024 + threadIdx.x;
    u32 v = (i < N_NODES) ? cnt[i] : 0u;
    s[threadIdx.x] = v; __syncthreads();
    for (int off = 1; off < 1024; off <<= 1) {
        u32 t = (threadIdx.x >= off) ? s[threadIdx.x - off] : 0u;
        __syncthreads(); s[threadIdx.x] += t; __syncthreads();
    }
    if (i < N_NODES) row_ptr[i] = s[threadIdx.x] - v;
    if (threadIdx.x == 1023) partials[blockIdx.x] = s[1023];
}

__global__ void k_scan_b(u32* partials) {
    __shared__ u32 s[128];
    u32 v = (threadIdx.x < 98) ? partials[threadIdx.x] : 0u;
    s[threadIdx.x] = v; __syncthreads();
    for (int off = 1; off < 128; off <<= 1) {
        u32 t = (threadIdx.x >= off) ? s[threadIdx.x - off] : 0u;
        __syncthreads(); s[threadIdx.x] += t; __syncthreads();
    }
    if (threadIdx.x < 98) partials[threadIdx.x] = s[threadIdx.x] - v;
}

__global__ void k_scan_c(u32* row_ptr, const u32* partials, u32* cursor) {
    int i = blockIdx.x * 1024 + threadIdx.x;
    if (i < N_NODES) {
        u32 r = row_ptr[i] + partials[blockIdx.x];
        row_ptr[i] = r; cursor[i] = r;
    }
}

// ---------------- bucketed CSR fill ----------------
#define FILL_K 20
#define FILL_C 625
__global__ __launch_bounds__(256) void k_fill(const int* __restrict__ src,
                                              const int* __restrict__ dst,
                                              u32* cursor, u32* col) {
    int bucket = blockIdx.x / FILL_C;
    int chunk  = blockIdx.x % FILL_C;
    int lo = bucket * (N_NODES / FILL_K);
    int hi = lo + (N_NODES / FILL_K);
    const int4* dst4 = (const int4*)dst;
    int base4 = chunk * 1280;
    for (int it = 0; it < 5; it++) {
        int i4 = base4 + it * 256 + threadIdx.x;
        int4 d = dst4[i4];
        int e = i4 * 4;
        #pragma unroll
        for (int c = 0; c < 4; c++) {
            int dv = (&d.x)[c];
            if (dv >= lo && dv < hi) {
                u32 p = atomicAdd(&cursor[dv], 1u);
                col[p] = (u32)src[e + c];
            }
        }
    }
}

// ---------------- encoder v3: LDS-staged, DRAM-friendly ----------------
// R1/R2 showed dur invariant to ILP and occupancy with HBM pinned at ~1.5 TB/s:
// the per-lane fragment loads (16 rows x 3072B stride per wave instruction)
// wreck DRAM row locality. v3: 16 rows/block; phase0 stages des (waves 0-1) and
// twt (waves 2-3) as CONTIGUOUS 48KB streams (each load instr = 2KB contiguous),
// fp32->bf16 in regs, ds_write to padded LDS [16][776] (pad => conflict-free
// ds_read_b128 fragments). Phase1: one (matrix,ntile) projection per wave from
// LDS + num/cat on waves 0/1. Phase2: W_in GEMM -> xs. 100000 = 6250*16 exactly.
__global__ __launch_bounds__(256) void k_encoder(
    const float* des, const float* twt, const float* nump, const float* catp,
    const u16* Fdes, const u16* Ftwt, const u16* Fnum, const u16* Fcat, const u16* Fin,
    const float* bdes, const float* btwt, const float* bnum, const float* bcat, const float* bin,
    const float* dinv, u16* xs) {
    __shared__ __align__(16) u16 As[2][16][776];   // 768 + 8 pad
    __shared__ __align__(16) u16 h0[16][136];
    int tid = threadIdx.x, wave = tid >> 6, lane = tid & 63, quad = lane >> 4, l16 = lane & 15;
    int rowbase = blockIdx.x * 16;
    int half = wave >> 1;            // 0: des, 1: twt

    // ---- phase 0: stage one matrix per wave-pair, contiguous 48KB stream ----
    {
        int t = tid & 127;           // thread index within the 128-thread half
        const float* X = half ? twt : des;
        const float4* X4 = (const float4*)(X + (size_t)rowbase * 768);
        #pragma unroll
        for (int rd = 0; rd < 3; rd++) {
            float4 v[8];
            #pragma unroll
            for (int q8 = 0; q8 < 8; q8++)
                v[q8] = X4[(rd * 8 + q8) * 128 + t];    // 128 lanes*16B = 2KB contiguous
            #pragma unroll
            for (int q8 = 0; q8 < 8; q8++) {
                int f = (rd * 8 + q8) * 512 + t * 4;    // flat float index, 4-group within row
                int r = f / 768, c = f - r * 768;
                u32 lo = (u32)f2bf(v[q8].x) | ((u32)f2bf(v[q8].y) << 16);
                u32 hi = (u32)f2bf(v[q8].z) | ((u32)f2bf(v[q8].w) << 16);
                *(uint2*)&As[half][r][c] = make_uint2(lo, hi);
            }
        }
    }
    __syncthreads();

    // ---- phase 1: projections (one matrix/ntile per wave) + num/cat ----
    {
        const u16* F = half ? Ftwt : Fdes;
        const float* B = half ? btwt : bdes;
        int nt = wave & 1;
        floatx4 c0 = {0, 0, 0, 0};
        #pragma unroll
        for (int kt = 0; kt < 24; kt++) {
            bf16x8 a = *(const bf16x8*)&As[half][l16][kt * 32 + quad * 8];
            bf16x8 b = *(const bf16x8*)(F + ((size_t)((kt * 2 + nt) * 64 + lane)) * 8);
            c0 = mfma_bf16(a, b, c0);
        }
        int cb = half * 32 + nt * 16;
        for (int r = 0; r < 4; r++)
            h0[quad * 4 + r][cb + l16] = f2bf(lrelu(c0[r] + B[nt * 16 + l16]));
    }
    if (wave < 2) {
        int arow = rowbase + l16;
        bfrag a;
        const float* P = wave ? catp : nump;
        int Kv = wave ? 11 : 6;
        const u16* F = wave ? Fcat : Fnum;
        const float* B = wave ? bcat : bnum;
        for (int j = 0; j < 8; j++) {
            int k = quad * 8 + j;
            a.u[j] = (k < Kv) ? f2bf(P[(size_t)arow * Kv + k]) : (u16)0;
        }
        floatx4 c0 = {0, 0, 0, 0}, c1 = {0, 0, 0, 0};
        bf16x8 b0 = *(const bf16x8*)(F + (size_t)(0 * 64 + lane) * 8);
        bf16x8 b1 = *(const bf16x8*)(F + (size_t)(1 * 64 + lane) * 8);
        c0 = mfma_bf16(a.v, b0, c0);
        c1 = mfma_bf16(a.v, b1, c1);
        int cb = 64 + wave * 32;
        for (int r = 0; r < 4; r++) {
            h0[quad * 4 + r][cb + l16]      = f2bf(lrelu(c0[r] + B[l16]));
            h0[quad * 4 + r][cb + 16 + l16] = f2bf(lrelu(c1[r] + B[16 + l16]));
        }
    }
    __syncthreads();

    // ---- phase 2: W_in GEMM (2 ntiles per wave) -> xs scaled by dinv ----
    {
        int n0 = wave * 2, n1 = wave * 2 + 1;
        floatx4 acc0 = {0, 0, 0, 0}, acc1 = {0, 0, 0, 0};
        #pragma unroll
        for (int ktl = 0; ktl < 4; ktl++) {
            bf16x8 a = *(const bf16x8*)&h0[l16][ktl * 32 + quad * 8];
            bf16x8 b0 = *(const bf16x8*)(Fin + (size_t)((ktl * 8 + n0) * 64 + lane) * 8);
            bf16x8 b1 = *(const bf16x8*)(Fin + (size_t)((ktl * 8 + n1) * 64 + lane) * 8);
            acc0 = mfma_bf16(a, b0, acc0);
            acc1 = mfma_bf16(a, b1, acc1);
        }
        for (int r = 0; r < 4; r++) {
            int grow = rowbase + quad * 4 + r;
            float dv = dinv[grow];
            float v0 = lrelu(acc0[r] + bin[n0 * 16 + l16]);
            float v1 = lrelu(acc1[r] + bin[n1 * 16 + l16]);
            xs[(size_t)grow * 128 + n0 * 16 + l16] = f2bf(dv * v0);
            xs[(size_t)grow * 128 + n1 * 16 + l16] = f2bf(dv * v1);
        }
    }
}

// ---------------- gather: zs[d] = bf16( dinv[d] * (sum_{s in N(d)} xs[s] + xs[d]) ) ----------------
__global__ __launch_bounds__(256) void k_gather(const u16* xs, u16* zs, const u32* row_ptr,
                                                const u32* cnt, const float* dinv, const u32* col) {
    int wave = threadIdx.x >> 6, lane = threadIdx.x & 63;
    int node = blockIdx.x * 4 + wave;
    const u32* xr = (const u32*)xs;
    u32 self = xr[(size_t)node * 64 + lane];
    float a0 = bf2f((u16)(self & 0xffff)), a1 = bf2f((u16)(self >> 16));
    u32 start = row_ptr[node];
    u32 m = cnt[node];
    for (u32 base = 0; base < m; base += 64) {
        u32 idx = base + lane;
        int c = (idx < m) ? (int)col[start + idx] : 0;
        int kmax = (int)min(64u, m - base);
        int j = 0;
        for (; j + 8 <= kmax; j += 8) {
            u32 w[8];
            #pragma unroll
            for (int q = 0; q < 8; q++) {
                int s = __shfl(c, j + q);
                w[q] = xr[(size_t)s * 64 + lane];
            }
            #pragma unroll
            for (int q = 0; q < 8; q++) {
                a0 += bf2f((u16)(w[q] & 0xffff));
                a1 += bf2f((u16)(w[q] >> 16));
            }
        }
        for (; j < kmax; j++) {
            int s = __shfl(c, j);
            u32 w = xr[(size_t)s * 64 + lane];
            a0 += bf2f((u16)(w & 0xffff));
            a1 += bf2f((u16)(w >> 16));
        }
    }
    float dv = dinv[node];
    u32 o = (u32)f2bf(dv * a0) | ((u32)f2bf(dv * a1) << 16);
    ((u32*)zs)[(size_t)node * 64 + lane] = o;
}

// ---------------- conv1 GEMM: xs = bf16( dinv[row] * (zs @ Wg1 + b_g1) ) ----------------
__global__ __launch_bounds__(256) void k_gemm_g1(const u16* zs, const u16* Fg1, const float* bg1,
                                                 const float* dinv, u16* xs) {
    int tid = threadIdx.x, wave = tid >> 6, lane = tid & 63, quad = lane >> 4, l16 = lane & 15;
    int rowbase = blockIdx.x * 64 + wave * 16;
    int arow = min(rowbase + l16, N_NODES - 1);
    floatx4 acc[8];
    for (int nt = 0; nt < 8; nt++) acc[nt] = (floatx4){0, 0, 0, 0};
    for (int kt = 0; kt < 4; kt++) {
        bf16x8 a = *(const bf16x8*)(zs + (size_t)arow * 128 + kt * 32 + quad * 8);
        for (int nt = 0; nt < 8; nt++) {
            bf16x8 b = *(const bf16x8*)(Fg1 + (size_t)((kt * 8 + nt) * 64 + lane) * 8);
            acc[nt] = mfma_bf16(a, b, acc[nt]);
        }
    }
    for (int nt = 0; nt < 8; nt++)
        for (int r = 0; r < 4; r++) {
            int grow = rowbase + quad * 4 + r;
            if (grow < N_NODES) {
                float v = acc[nt][r] + bg1[nt * 16 + l16];
                xs[(size_t)grow * 128 + nt * 16 + l16] = f2bf(dinv[grow] * v);
            }
        }
}

// ---------------- tail: conv2 GEMM + o1 GEMM(lrelu) + o2 dots (fp32 out) ----------------
__global__ __launch_bounds__(256) void k_tail(const u16* zs, const u16* Fg2, const float* bg2,
                                              const u16* Fo1, const float* bo1,
                                              const float* Wo2, const float* bo2, float* out) {
    __shared__ u16 t0[64][136];
    __shared__ float t1[64][130];
    int tid = threadIdx.x, wave = tid >> 6, lane = tid & 63, quad = lane >> 4, l16 = lane & 15;
    int rowbase = blockIdx.x * 64 + wave * 16;
    int arow = min(rowbase + l16, N_NODES - 1);
    floatx4 acc[8];
    for (int nt = 0; nt < 8; nt++) acc[nt] = (floatx4){0, 0, 0, 0};
    for (int kt = 0; kt < 4; kt++) {
        bf16x8 a = *(const bf16x8*)(zs + (size_t)arow * 128 + kt * 32 + quad * 8);
        for (int nt = 0; nt < 8; nt++) {
            bf16x8 b = *(const bf16x8*)(Fg2 + (size_t)((kt * 8 + nt) * 64 + lane) * 8);
            acc[nt] = mfma_bf16(a, b, acc[nt]);
        }
    }
    for (int nt = 0; nt < 8; nt++)
        for (int r = 0; r < 4; r++) {
            int rl = wave * 16 + quad * 4 + r;
            t0[rl][nt * 16 + l16] = f2bf(acc[nt][r] + bg2[nt * 16 + l16]);
        }
    __syncthreads();
    for (int nt = 0; nt < 8; nt++) acc[nt] = (floatx4){0, 0, 0, 0};
    for (int kt = 0; kt < 4; kt++) {
        bf16x8 a = *(const bf16x8*)&t0[wave * 16 + l16][kt * 32 + quad * 8];
        for (int nt = 0; nt < 8; nt++) {
            bf16x8 b = *(const bf16x8*)(Fo1 + (size_t)((kt * 8 + nt) * 64 + lane) * 8);
            acc[nt] = mfma_bf16(a, b, acc[nt]);
        }
    }
    for (int nt = 0; nt < 8; nt++)
        for (int r = 0; r < 4; r++) {
            int rl = wave * 16 + quad * 4 + r;
            t1[rl][nt * 16 + l16] = lrelu(acc[nt][r] + bo1[nt * 16 + l16]);
        }
    __syncthreads();
    if (tid < 128) {
        int nl = tid >> 1, j = tid & 1;
        int grow = blockIdx.x * 64 + nl;
        if (grow < N_NODES) {
            float s = bo2[j];
            for (int k = 0; k < 128; k++) s += t1[nl][k] * Wo2[k * 2 + j];
            out[(size_t)grow * 2 + j] = s;
        }
    }
}

extern "C" void kernel_launch(void* const* d_in, const int* in_sizes, int n_in,
                              void* d_out, int out_size, void* d_ws, size_t ws_size,
                              hipStream_t stream) {
    const float* des  = (const float*)d_in[0];
    const float* twt  = (const float*)d_in[1];
    const float* nump = (const float*)d_in[2];
    const float* catp = (const float*)d_in[3];
    const int* ei   = (const int*)d_in[4];
    const int* esrc = ei;
    const int* edst = ei + N_EDGES;
    const float* Wdes = (const float*)d_in[6];  const float* bdes = (const float*)d_in[7];
    const float* Wtwt = (const float*)d_in[8];  const float* btwt = (const float*)d_in[9];
    const float* Wnum = (const float*)d_in[10]; const float* bnum = (const float*)d_in[11];
    const float* Wcat = (const float*)d_in[12]; const float* bcat = (const float*)d_in[13];
    const float* Win  = (const float*)d_in[14]; const float* bin  = (const float*)d_in[15];
    const float* Wg1  = (const float*)d_in[16]; const float* bg1  = (const float*)d_in[17];
    const float* Wg2  = (const float*)d_in[18]; const float* bg2  = (const float*)d_in[19];
    const float* Wo1  = (const float*)d_in[20]; const float* bo1  = (const float*)d_in[21];
    const float* Wo2  = (const float*)d_in[22]; const float* bo2  = (const float*)d_in[23];

    char* ws = (char*)d_ws;
    size_t off = 0;
    auto alloc = [&](size_t b) { off = (off + 511) & ~(size_t)511; size_t o = off; off += b; return o; };
    u16* Fdes = (u16*)(ws + alloc(49152));
    u16* Ftwt = (u16*)(ws + alloc(49152));
    u16* Fnum = (u16*)(ws + alloc(2048));
    u16* Fcat = (u16*)(ws + alloc(2048));
    u16* Fin  = (u16*)(ws + alloc(32768));
    u16* Fg1  = (u16*)(ws + alloc(32768));
    u16* Fg2  = (u16*)(ws + alloc(32768));
    u16* Fo1  = (u16*)(ws + alloc(32768));
    u32* cnt     = (u32*)(ws + alloc((size_t)N_NODES * 4));
    float* dinv  = (float*)(ws + alloc((size_t)N_NODES * 4));
    u32* row_ptr = (u32*)(ws + alloc((size_t)(N_NODES + 1) * 4));
    u32* cursor  = (u32*)(ws + alloc((size_t)N_NODES * 4));
    u32* partials= (u32*)(ws + alloc(1024));
    u32* col     = (u32*)(ws + alloc((size_t)N_EDGES * 4));
    u16* xs      = (u16*)(ws + alloc((size_t)N_NODES * 128 * 2));
    u16* zs      = (u16*)(ws + alloc((size_t)N_NODES * 128 * 2));

    hipMemsetAsync(cnt, 0, (size_t)N_NODES * 4, stream);
    k_prep<<<57, 256, 0, stream>>>(Wdes, Wtwt, Wnum, Wcat, Win, Wg1, Wg2, Wo1,
                                   Fdes, Ftwt, Fnum, Fcat, Fin, Fg1, Fg2, Fo1);
    k_hist<<<N_EDGES / 256, 256, 0, stream>>>(edst, cnt);
    k_dinv<<<(N_NODES + 255) / 256, 256, 0, stream>>>(cnt, dinv);
    k_scan_a<<<98, 1024, 0, stream>>>(cnt, row_ptr, partials);
    k_scan_b<<<1, 128, 0, stream>>>(partials);
    k_scan_c<<<98, 1024, 0, stream>>>(row_ptr, partials, cursor);
    k_fill<<<FILL_K * FILL_C, 256, 0, stream>>>(esrc, edst, cursor, col);
    k_encoder<<<6250, 256, 0, stream>>>(des, twt, nump, catp,
                                        Fdes, Ftwt, Fnum, Fcat, Fin,
                                        bdes, btwt, bnum, bcat, bin, dinv, xs);
    k_gather<<<25000, 256, 0, stream>>>(xs, zs, row_ptr, cnt, dinv, col);
    k_gemm_g1<<<1563, 256, 0, stream>>>(zs, Fg1, bg1, dinv, xs);
    k_gather<<<25000, 256, 0, stream>>>(xs, zs, row_ptr, cnt, dinv, col);
    k_tail<<<1563, 256, 0, stream>>>(zs, Fg2, bg2, Fo1, bo1, Wo2, bo2, (float*)d_out);
}